// Round 1
// baseline (303.988 us; speedup 1.0000x reference)
//
#include <hip/hip_runtime.h>
#include <math.h>

// NLM denoise, S=21 search window, 256x256x3 image, reflect padding.
// Block = 16x16 pixel tile x offset-group (gridDim.z groups of the 441 offsets).
// LDS staging: Yreg 56x56 luminance (covers double-reflect taps), Creg 3x36x36
// reflected RGB halo. Per offset: d on 36x36, separable 21-tap box sums
// (horizontal via 4-wide sliding windows on 144 threads), weight+accumulate in
// registers. Partials per group -> ws; finalize kernel reduces/divides/clips.

#define SRCH 21
#define PAD 10
#define TILE 16
#define DT 36      // TILE + 2*PAD  (dilated tile)
#define YR 56      // TILE + 4*PAD  (luminance region)
#define IMG 256
#define NPIX (IMG * IMG)

__device__ __forceinline__ int refl(int t) {
    // reflect ('mirror without edge repeat') for t in [-255, 510]
    t = t < 0 ? -t : t;
    return t > 255 ? 510 - t : t;
}

__global__ __launch_bounds__(256, 4)
void nlm_main(const float* __restrict__ rgb, const float* __restrict__ hptr,
              float* __restrict__ partials)
{
    __shared__ float Yreg[YR][YR + 1];          // 56x57 = 12768 B
    __shared__ float Creg[3][DT][DT + 1];       // 3x36x37 = 15984 B
    __shared__ float dbuf[DT][DT + 1];          // 36x37 = 5328 B
    __shared__ float hsbuf[DT][TILE + 1];       // 36x17 = 2448 B
    __shared__ int Mi[DT], Mj[DT];

    const int tid = threadIdx.x;
    const int tj = blockIdx.x * TILE;
    const int ti = blockIdx.y * TILE;

    // Region covering every y-coordinate this tile can touch (incl. double reflect):
    // coords subset of [max(0,ti-20), min(255,ti+35)] -> width <= 56.
    const int base_i = min(max(ti - 2 * PAD, 0), IMG - YR);
    const int base_j = min(max(tj - 2 * PAD, 0), IMG - YR);

    // --- stage luminance region (clipped rgb -> y) ---
    for (int idx = tid; idx < YR * YR; idx += 256) {
        int a = idx / YR, b = idx - a * YR;
        int gi = base_i + a, gj = base_j + b;
        float r  = rgb[0 * NPIX + gi * IMG + gj];
        float g  = rgb[1 * NPIX + gi * IMG + gj];
        float bl = rgb[2 * NPIX + gi * IMG + gj];
        r  = fminf(fmaxf(r,  0.f), 1.f);
        g  = fminf(fmaxf(g,  0.f), 1.f);
        bl = fminf(fmaxf(bl, 0.f), 1.f);
        Yreg[a][b] = 0.299f * r + 0.587f * g + 0.114f * bl;
    }
    // --- stage reflected RGB halo (UNclipped rgb, matches rgb_ws) ---
    for (int idx = tid; idx < 3 * DT * DT; idx += 256) {
        int c = idx / (DT * DT);
        int rem = idx - c * (DT * DT);
        int a = rem / DT, b = rem - a * DT;
        Creg[c][a][b] = rgb[c * NPIX + refl(ti + a - PAD) * IMG + refl(tj + b - PAD)];
    }
    if (tid < DT) {
        Mi[tid] = refl(ti + tid - PAD);
        Mj[tid] = refl(tj + tid - PAD);
    }

    const float hv = fmaxf(hptr[0], 0.f);
    const float invh = 1.0f / (hv + 1e-8f);

    const int pa = tid >> 4;    // pixel row in tile
    const int pb = tid & 15;    // pixel col in tile
    float aR = 0.f, aG = 0.f, aB = 0.f, aW = 0.f;

    __syncthreads();

    const int nOff = SRCH * SRCH;
    for (int o = (int)blockIdx.z; o < nOff; o += (int)gridDim.z) {
        const int du = o / SRCH - PAD;
        const int dv = (o - (o / SRCH) * SRCH) - PAD;

        // d[a][b] = (y[m] - y[r(m+o)])^2 at window position m = (Mi[a], Mj[b])
        for (int idx = tid; idx < DT * DT; idx += 256) {
            int a = idx / DT, b = idx - a * DT;
            int mi = Mi[a], mj = Mj[b];
            float y0 = Yreg[mi - base_i][mj - base_j];
            float y1 = Yreg[refl(mi + du) - base_i][refl(mj + dv) - base_j];
            float dd = y0 - y1;
            dbuf[a][b] = dd * dd;
        }
        __syncthreads();

        // horizontal 21-tap sums: 36 rows x 16 outputs; 144 threads, 4-wide sliding
        if (tid < 144) {
            int a  = tid >> 2;
            int b0 = (tid & 3) * 4;
            float s = 0.f;
            #pragma unroll
            for (int k = 0; k < SRCH; ++k) s += dbuf[a][b0 + k];
            hsbuf[a][b0] = s;
            #pragma unroll
            for (int j = 1; j < 4; ++j) {
                s += dbuf[a][b0 + SRCH - 1 + j] - dbuf[a][b0 + j - 1];
                hsbuf[a][b0 + j] = s;
            }
        }
        __syncthreads();

        // vertical 21-tap + weight + accumulate (one pixel per thread)
        float vs = 0.f;
        #pragma unroll
        for (int k = 0; k < SRCH; ++k) vs += hsbuf[pa + k][pb];
        float dist = sqrtf(fmaxf(vs, 0.f));
        float w = __expf(-dist * invh);
        aW += w;
        aR += w * Creg[0][pa + du + PAD][pb + dv + PAD];
        aG += w * Creg[1][pa + du + PAD][pb + dv + PAD];
        aB += w * Creg[2][pa + du + PAD][pb + dv + PAD];
        // no barrier needed here: next d-write is fenced by the post-d barrier,
        // and consume only reads hsbuf/Creg which hs-phase rewrites after a barrier.
    }

    const size_t gbase = (size_t)blockIdx.z * 4 * NPIX;
    const int pix = (ti + pa) * IMG + (tj + pb);
    partials[gbase + 0 * NPIX + pix] = aR;
    partials[gbase + 1 * NPIX + pix] = aG;
    partials[gbase + 2 * NPIX + pix] = aB;
    partials[gbase + 3 * NPIX + pix] = aW;
}

__global__ __launch_bounds__(256)
void nlm_finalize(const float* __restrict__ partials, float* __restrict__ out, int nG)
{
    int idx = blockIdx.x * blockDim.x + threadIdx.x;
    if (idx >= NPIX) return;
    float r = 0.f, g = 0.f, b = 0.f, w = 0.f;
    for (int gg = 0; gg < nG; ++gg) {
        const float* base = partials + (size_t)gg * 4 * NPIX;
        r += base[0 * NPIX + idx];
        g += base[1 * NPIX + idx];
        b += base[2 * NPIX + idx];
        w += base[3 * NPIX + idx];
    }
    float inv = 1.0f / w;   // w >= 1 (offset (0,0) contributes exp(0))
    out[0 * NPIX + idx] = fminf(fmaxf(r * inv, 0.f), 1.f);
    out[1 * NPIX + idx] = fminf(fmaxf(g * inv, 0.f), 1.f);
    out[2 * NPIX + idx] = fminf(fmaxf(b * inv, 0.f), 1.f);
}

extern "C" void kernel_launch(void* const* d_in, const int* in_sizes, int n_in,
                              void* d_out, int out_size, void* d_ws, size_t ws_size,
                              hipStream_t stream) {
    (void)in_sizes; (void)n_in; (void)out_size;
    const float* rgb  = (const float*)d_in[0];
    const float* hptr = (const float*)d_in[1];
    float* out = (float*)d_out;
    float* partials = (float*)d_ws;

    // 4 offset-groups (4.2 MB partials) if workspace allows, else 1 (1.05 MB).
    int nG = (ws_size >= (size_t)4 * 4 * NPIX * sizeof(float)) ? 4 : 1;

    dim3 grid(IMG / TILE, IMG / TILE, nG);   // 16 x 16 x nG
    nlm_main<<<grid, 256, 0, stream>>>(rgb, hptr, partials);
    nlm_finalize<<<NPIX / 256, 256, 0, stream>>>(partials, out, nG);
}

// Round 3
// 179.020 us; speedup vs baseline: 1.6981x; 1.6981x over previous
//
#include <hip/hip_runtime.h>
#include <math.h>

// NLM S=21, 256x256x3, reflect padding. Round 2 restructure (R3: fix compile):
// 32x32 tile/block, fused f+h-slide phase -> transposed hs (hsT), vertical
// sliding per 1x4 thread-strip, fp16 LDS staging, interior fast path,
// atomic global accumulation over 24 offset-groups.

#define IMG 256
#define NPIX (IMG * IMG)
#define TILE 32
#define GR 52      // TILE + 20 (window-grid dim)
#define YD 72      // TILE + 40 (Y region dim)
#define YSTR 76    // Yreg row stride in halves (152B; dword-stride 38 ~ 2-way max)
#define GSTR 60    // Ygrid row stride in halves (120B, 8B-aligned rows for b64)
#define HSTR 53    // hsT row stride in dwords (odd -> conflict-free)
#define NOFF 441
#define NG 24

typedef __attribute__((ext_vector_type(4))) _Float16 half4;

__device__ __forceinline__ int refl(int t) {
    t = t < 0 ? -t : t;             // valid for t in [-255, 510]
    return t > 255 ? 510 - t : t;
}

__global__ __launch_bounds__(256, 3)
void nlm_main(const float* __restrict__ rgb, const float* __restrict__ hptr,
              float* __restrict__ partials)
{
    __shared__ _Float16 Yreg[YD][YSTR];        // 10944 B  (y, fp16)
    __shared__ _Float16 Ygrid[GR][GSTR];       //  6240 B  (y at window-grid coords)
    __shared__ _Float16 Creg4[GR][GR + 1][4];  // 22048 B  (RGBX taps, b64-readable)
    __shared__ float    hsT[TILE][HSTR];       //  6784 B  (transposed h-sums)

    const int tid = threadIdx.x;
    const int tj = (blockIdx.x & 7) * TILE;
    const int ti = (blockIdx.x >> 3) * TILE;

    const int Ybi = min(max(ti - 20, 0), IMG - YD);
    const int Ybj = min(max(tj - 20, 0), IMG - YD);
    // all raw coords ti-10+t+du lie in [ti-20, ti+51]; identity-refl iff:
    const bool interior = (ti >= 20) && (ti + 51 <= 255) && (tj >= 20) && (tj + 51 <= 255);

    // ---- stage Y (clipped luminance, fp16) ----
    for (int idx = tid; idx < YD * YD; idx += 256) {
        int a = idx / YD, b = idx - a * YD;
        int g = (Ybi + a) * IMG + (Ybj + b);
        float r  = fminf(fmaxf(rgb[g], 0.f), 1.f);
        float gg = fminf(fmaxf(rgb[NPIX + g], 0.f), 1.f);
        float bb = fminf(fmaxf(rgb[2 * NPIX + g], 0.f), 1.f);
        Yreg[a][b] = (_Float16)(0.299f * r + 0.587f * gg + 0.114f * bb);
    }
    // ---- stage RGBX taps at window-grid coords (UNclipped rgb) ----
    for (int idx = tid; idx < GR * GR; idx += 256) {
        int t = idx / GR, b = idx - t * GR;
        int g = refl(ti - 10 + t) * IMG + refl(tj - 10 + b);
        half4 c;
        c.x = (_Float16)rgb[g];
        c.y = (_Float16)rgb[NPIX + g];
        c.z = (_Float16)rgb[2 * NPIX + g];
        c.w = (_Float16)0.f;
        *(half4*)&Creg4[t][b][0] = c;
    }
    __syncthreads();
    // ---- stage Ygrid (y at window-grid coords; aligned b64 reads in H) ----
    for (int idx = tid; idx < GR * GR; idx += 256) {
        int t = idx / GR, b = idx - t * GR;
        Ygrid[t][b] = Yreg[refl(ti - 10 + t) - Ybi][refl(tj - 10 + b) - Ybj];
    }

    const float hv = fmaxf(hptr[0], 0.f);
    const float invh = 1.0f / (hv + 1e-8f);

    const int pb = tid & 31;            // pixel col in tile
    const int s4 = (tid >> 5) << 2;     // strip start row (0,4,...,28)
    float aR[4] = {0.f, 0.f, 0.f, 0.f};
    float aG[4] = {0.f, 0.f, 0.f, 0.f};
    float aB[4] = {0.f, 0.f, 0.f, 0.f};
    float aW[4] = {0.f, 0.f, 0.f, 0.f};

    for (int o = (int)blockIdx.y; o < NOFF; o += NG) {
        const int oq = o / 21;
        const int du = oq - 10;
        const int dv = (o - oq * 21) - 10;

        __syncthreads();   // Ygrid staged (iter 0) / hsT consumed (later iters)

        // ---- fused f + horizontal slide: 52 rows x 4 chunks of 8 outputs ----
        if (tid < 4 * GR) {
            const int chunk = tid / GR;          // 0..3 (chunk-major: lanes t-consecutive)
            const int t = tid - chunk * GR;      // 0..51
            const int c0 = chunk * 8;

            int r2;
            if (interior) r2 = t + 10 + du;
            else          r2 = refl(refl(ti - 10 + t) + du) - Ybi;
            const _Float16* y1row = &Yreg[r2][0];

            float y0[28];
            #pragma unroll
            for (int i = 0; i < 7; ++i) {
                half4 v = *(const half4*)&Ygrid[t][c0 + 4 * i];
                y0[4 * i + 0] = (float)v.x;
                y0[4 * i + 1] = (float)v.y;
                y0[4 * i + 2] = (float)v.z;
                y0[4 * i + 3] = (float)v.w;
            }
            float f[28];
            if (interior) {
                const int cb = c0 + 10 + dv;     // consecutive cols, no refl
                #pragma unroll
                for (int j = 0; j < 28; ++j) {
                    float d = y0[j] - (float)y1row[cb + j];
                    f[j] = d * d;
                }
            } else {
                #pragma unroll
                for (int j = 0; j < 28; ++j) {
                    int cj = refl(refl(tj - 10 + c0 + j) + dv) - Ybj;
                    float d = y0[j] - (float)y1row[cj];
                    f[j] = d * d;
                }
            }
            float s = 0.f;
            #pragma unroll
            for (int j = 0; j < 21; ++j) s += f[j];
            hsT[c0][t] = s;
            #pragma unroll
            for (int k = 1; k < 8; ++k) {
                s += f[20 + k] - f[k - 1];
                hsT[c0 + k][t] = s;
            }
        }
        __syncthreads();

        // ---- vertical slide + weight + accumulate (1x4 strip per thread) ----
        float vs = 0.f;
        #pragma unroll
        for (int u = 0; u < 21; ++u) vs += hsT[pb][s4 + u];
        const int cr = 10 + du;
        const int cc = pb + 10 + dv;
        #pragma unroll
        for (int k = 0; k < 4; ++k) {
            float dist = sqrtf(fmaxf(vs, 0.f));
            float w = __expf(-dist * invh);
            half4 c = *(const half4*)&Creg4[s4 + k + cr][cc][0];
            aW[k] += w;
            aR[k] += w * (float)c.x;
            aG[k] += w * (float)c.y;
            aB[k] += w * (float)c.z;
            if (k < 3) vs += hsT[pb][s4 + k + 21] - hsT[pb][s4 + k];
        }
    }

    // ---- epilogue: atomic accumulate partials ----
    #pragma unroll
    for (int k = 0; k < 4; ++k) {
        int gpix = (ti + s4 + k) * IMG + (tj + pb);
        atomicAdd(&partials[0 * NPIX + gpix], aR[k]);
        atomicAdd(&partials[1 * NPIX + gpix], aG[k]);
        atomicAdd(&partials[2 * NPIX + gpix], aB[k]);
        atomicAdd(&partials[3 * NPIX + gpix], aW[k]);
    }
}

__global__ __launch_bounds__(256)
void nlm_finalize(const float* __restrict__ partials, float* __restrict__ out)
{
    int idx = blockIdx.x * blockDim.x + threadIdx.x;
    float inv = 1.0f / partials[3 * NPIX + idx];   // sum(w) >= 1 (self offset)
    out[idx]            = fminf(fmaxf(partials[idx] * inv, 0.f), 1.f);
    out[NPIX + idx]     = fminf(fmaxf(partials[NPIX + idx] * inv, 0.f), 1.f);
    out[2 * NPIX + idx] = fminf(fmaxf(partials[2 * NPIX + idx] * inv, 0.f), 1.f);
}

extern "C" void kernel_launch(void* const* d_in, const int* in_sizes, int n_in,
                              void* d_out, int out_size, void* d_ws, size_t ws_size,
                              hipStream_t stream) {
    (void)in_sizes; (void)n_in; (void)out_size; (void)ws_size;
    const float* rgb  = (const float*)d_in[0];
    const float* hptr = (const float*)d_in[1];
    float* out = (float*)d_out;
    float* partials = (float*)d_ws;   // 4 * NPIX floats = 1.05 MB (<= ws, proven R1)

    (void)hipMemsetAsync(partials, 0, (size_t)4 * NPIX * sizeof(float), stream);
    dim3 grid(64, NG);                 // 64 tiles x 24 offset-groups = 1536 blocks
    nlm_main<<<grid, 256, 0, stream>>>(rgb, hptr, partials);
    nlm_finalize<<<NPIX / 256, 256, 0, stream>>>(partials, out);
}

// Round 4
// 171.868 us; speedup vs baseline: 1.7687x; 1.0416x over previous
//
#include <hip/hip_runtime.h>
#include <math.h>

// NLM S=21, 256x256x3, reflect padding. Round 4:
// - persistent y0 in VGPRs (Ygrid LDS array deleted) -> LDS 40.6KB = 4 blocks/CU
// - precomputed u8 column-refl tables for edge tiles (kills per-offset refl chains)
// - strip-8 vertical slide (128 threads x 8 px)
// - ws-gated direct-store partials (no atomics, no memset) + 24-group finalize
// - incremental du/dv (no integer division in the offset loop)

#define IMG 256
#define NPIX (IMG * IMG)
#define TILE 32
#define GR 52      // TILE + 20 (window-grid dim)
#define YD 72      // TILE + 40 (Y region dim)
#define YSTR 77    // Yreg row stride in halves (38.5 dwords -> well-spread banks)
#define HSTR 53    // hsT row stride in dwords (odd -> conflict-free)
#define NOFF 441
#define NG 24

typedef __attribute__((ext_vector_type(4))) _Float16 half4;

__device__ __forceinline__ int refl(int t) {
    t = t < 0 ? -t : t;             // valid for t in [-255, 510]
    return t > 255 ? 510 - t : t;
}

template <bool DIRECT>
__global__ __launch_bounds__(256, 4)
void nlm_main(const float* __restrict__ rgb, const float* __restrict__ hptr,
              float* __restrict__ partials)
{
    __shared__ _Float16 Yreg[YD][YSTR];          // 11088 B (clipped luminance, fp16)
    __shared__ _Float16 Creg4[GR][GR][4];        // 21632 B (RGBX taps at window grid)
    __shared__ float    hsT[TILE][HSTR];         //  6784 B (transposed h-sums)
    __shared__ unsigned char cjTab[21][GR];      //  1092 B (edge col refl maps, per dv)
    // total 40596 B -> rounds to 40960 -> exactly 4 blocks/CU

    const int tid = threadIdx.x;
    const int tj = ((int)blockIdx.x & 7) * TILE;
    const int ti = ((int)blockIdx.x >> 3) * TILE;

    const int Ybi = min(max(ti - 20, 0), IMG - YD);
    const int Ybj = min(max(tj - 20, 0), IMG - YD);
    const bool interior = (ti >= 20) && (ti + 51 <= 255) && (tj >= 20) && (tj + 51 <= 255);

    // ---- stage Y (clipped luminance, fp16) ----
    for (int idx = tid; idx < YD * YD; idx += 256) {
        int a = idx / YD, b = idx - a * YD;
        int g = (Ybi + a) * IMG + (Ybj + b);
        float r  = fminf(fmaxf(rgb[g], 0.f), 1.f);
        float gg = fminf(fmaxf(rgb[NPIX + g], 0.f), 1.f);
        float bb = fminf(fmaxf(rgb[2 * NPIX + g], 0.f), 1.f);
        Yreg[a][b] = (_Float16)(0.299f * r + 0.587f * gg + 0.114f * bb);
    }
    // ---- stage RGBX taps at window-grid coords (UNclipped rgb) ----
    for (int idx = tid; idx < GR * GR; idx += 256) {
        int t = idx / GR, b = idx - t * GR;
        int g = refl(ti - 10 + t) * IMG + refl(tj - 10 + b);
        half4 c;
        c.x = (_Float16)rgb[g];
        c.y = (_Float16)rgb[NPIX + g];
        c.z = (_Float16)rgb[2 * NPIX + g];
        c.w = (_Float16)0.f;
        *(half4*)&Creg4[t][b][0] = c;
    }
    // ---- edge tiles: precompute column refl maps for all 21 dv ----
    if (!interior) {
        for (int idx = tid; idx < 21 * GR; idx += 256) {
            int d = idx / GR, c = idx - d * GR;
            cjTab[d][c] = (unsigned char)(refl(refl(tj - 10 + c) + (d - 10)) - Ybj);
        }
    }
    __syncthreads();

    // ---- persistent y0 (window-grid luminance for this thread's h-task) ----
    const int chunk = tid / GR;              // 0..3 for tid<208
    const int t     = tid - chunk * GR;      // 0..51
    const int c0    = chunk * 8;
    float y0r[28];
    if (tid < 4 * GR) {
        int ri = refl(ti - 10 + t) - Ybi;
        #pragma unroll
        for (int j = 0; j < 28; ++j) {
            int cj = refl(tj - 10 + c0 + j) - Ybj;
            y0r[j] = (float)Yreg[ri][cj];
        }
    }

    const float hv = fmaxf(hptr[0], 0.f);
    const float invh = 1.0f / (hv + 1e-8f);

    const int pb = tid & 31;                 // pixel col (v-phase, tid<128)
    const int s8 = (tid >> 5) << 3;          // strip start row (0,8,16,24)
    float aR[8], aG[8], aB[8], aW[8];
    #pragma unroll
    for (int k = 0; k < 8; ++k) { aR[k] = 0.f; aG[k] = 0.f; aB[k] = 0.f; aW[k] = 0.f; }

    int du = ((int)blockIdx.y / 21) - 10;
    int dv = ((int)blockIdx.y % 21) - 10;

    for (int o = (int)blockIdx.y; o < NOFF; o += NG) {
        __syncthreads();   // hsT consumed by previous iteration's v-phase

        // ---- fused f + horizontal slide: 52 rows x 4 chunks of 8 outputs ----
        if (tid < 4 * GR) {
            int r2;
            if (interior) r2 = t + 10 + du;
            else          r2 = refl(refl(ti - 10 + t) + du) - Ybi;
            const _Float16* y1row = &Yreg[r2][0];

            float f[28];
            if (interior) {
                const int cb = c0 + 10 + dv;
                #pragma unroll
                for (int j = 0; j < 28; ++j) {
                    float d = y0r[j] - (float)y1row[cb + j];
                    f[j] = d * d;
                }
            } else {
                const unsigned char* cj = &cjTab[dv + 10][0];
                #pragma unroll
                for (int j = 0; j < 28; ++j) {
                    float d = y0r[j] - (float)y1row[cj[c0 + j]];
                    f[j] = d * d;
                }
            }
            float s = 0.f;
            #pragma unroll
            for (int j = 0; j < 21; ++j) s += f[j];
            hsT[c0][t] = s;
            #pragma unroll
            for (int k = 1; k < 8; ++k) {
                s += f[20 + k] - f[k - 1];
                hsT[c0 + k][t] = s;
            }
        }
        __syncthreads();

        // ---- vertical slide + weight + accumulate (1x8 strip per thread) ----
        if (tid < 128) {
            float vs = 0.f;
            #pragma unroll
            for (int u = 0; u < 21; ++u) vs += hsT[pb][s8 + u];
            const int cr = 10 + du;
            const int cc = pb + 10 + dv;
            #pragma unroll
            for (int k = 0; k < 8; ++k) {
                float dist = sqrtf(fmaxf(vs, 0.f));
                float w = __expf(-dist * invh);
                half4 c = *(const half4*)&Creg4[s8 + k + cr][cc][0];
                aW[k] += w;
                aR[k] += w * (float)c.x;
                aG[k] += w * (float)c.y;
                aB[k] += w * (float)c.z;
                if (k < 7) vs += hsT[pb][s8 + k + 21] - hsT[pb][s8 + k];
            }
        }

        // advance offset by NG=24 (= 21 + 3)
        du += 1; dv += 3;
        if (dv > 10) { dv -= 21; du += 1; }
    }

    // ---- epilogue ----
    if (tid < 128) {
        #pragma unroll
        for (int k = 0; k < 8; ++k) {
            int gpix = (ti + s8 + k) * IMG + (tj + pb);
            if (DIRECT) {
                float* base = partials + (size_t)blockIdx.y * 4 * NPIX;
                base[0 * NPIX + gpix] = aR[k];
                base[1 * NPIX + gpix] = aG[k];
                base[2 * NPIX + gpix] = aB[k];
                base[3 * NPIX + gpix] = aW[k];
            } else {
                atomicAdd(&partials[0 * NPIX + gpix], aR[k]);
                atomicAdd(&partials[1 * NPIX + gpix], aG[k]);
                atomicAdd(&partials[2 * NPIX + gpix], aB[k]);
                atomicAdd(&partials[3 * NPIX + gpix], aW[k]);
            }
        }
    }
}

__global__ __launch_bounds__(256)
void nlm_finalize(const float* __restrict__ partials, float* __restrict__ out, int nG)
{
    int idx = blockIdx.x * blockDim.x + threadIdx.x;
    float r = 0.f, g = 0.f, b = 0.f, w = 0.f;
    for (int gg = 0; gg < nG; ++gg) {
        const float* base = partials + (size_t)gg * 4 * NPIX;
        r += base[0 * NPIX + idx];
        g += base[1 * NPIX + idx];
        b += base[2 * NPIX + idx];
        w += base[3 * NPIX + idx];
    }
    float inv = 1.0f / w;   // sum(w) >= 1 (self offset contributes exp(0))
    out[idx]            = fminf(fmaxf(r * inv, 0.f), 1.f);
    out[NPIX + idx]     = fminf(fmaxf(g * inv, 0.f), 1.f);
    out[2 * NPIX + idx] = fminf(fmaxf(b * inv, 0.f), 1.f);
}

extern "C" void kernel_launch(void* const* d_in, const int* in_sizes, int n_in,
                              void* d_out, int out_size, void* d_ws, size_t ws_size,
                              hipStream_t stream) {
    (void)in_sizes; (void)n_in; (void)out_size;
    const float* rgb  = (const float*)d_in[0];
    const float* hptr = (const float*)d_in[1];
    float* out = (float*)d_out;
    float* partials = (float*)d_ws;

    const bool direct = ws_size >= (size_t)NG * 4 * NPIX * sizeof(float);  // 25.2 MB
    dim3 grid(64, NG);
    if (direct) {
        nlm_main<true><<<grid, 256, 0, stream>>>(rgb, hptr, partials);
        nlm_finalize<<<NPIX / 256, 256, 0, stream>>>(partials, out, NG);
    } else {
        (void)hipMemsetAsync(partials, 0, (size_t)4 * NPIX * sizeof(float), stream);
        nlm_main<false><<<grid, 256, 0, stream>>>(rgb, hptr, partials);
        nlm_finalize<<<NPIX / 256, 256, 0, stream>>>(partials, out, 1);
    }
}

// Round 5
// 135.659 us; speedup vs baseline: 2.2408x; 1.2669x over previous
//
#include <hip/hip_runtime.h>
#include <math.h>

// NLM S=21, 256x256x3, reflect padding. Round 5:
// - finalize: compile-time NG unroll + float4 partials layout (fix serialized
//   HBM latency that made the inter-kernel gap ~59us)
// - v-phase on all 256 threads (strip-4), paired slide reads
// - h-phase interior: half2-vectorized y1 loads (YSTR=78: dword-aligned rows,
//   39-dword stride => full bank spread), uniform even/odd dv branch
// - epilogue: one float4 store per pixel

#define IMG 256
#define NPIX (IMG * IMG)
#define TILE 32
#define GR 52      // TILE + 20 (window-grid dim)
#define YD 72      // TILE + 40 (Y region dim)
#define YSTR 78    // Yreg row stride in halves: rows dword-aligned; 39-dword stride
#define HSTR 53    // hsT row stride in dwords (odd -> conflict-free)
#define NOFF 441
#define NG 24

typedef __attribute__((ext_vector_type(4))) _Float16 half4;
typedef __attribute__((ext_vector_type(2))) _Float16 half2_t;

__device__ __forceinline__ int refl(int t) {
    t = t < 0 ? -t : t;             // valid for t in [-255, 510]
    return t > 255 ? 510 - t : t;
}

template <bool DIRECT>
__global__ __launch_bounds__(256, 4)
void nlm_main(const float* __restrict__ rgb, const float* __restrict__ hptr,
              float4* __restrict__ partials)
{
    __shared__ _Float16 Yreg[YD][YSTR];          // 11232 B (clipped luminance, fp16)
    __shared__ _Float16 Creg4[GR][GR][4];        // 21632 B (RGBX taps at window grid)
    __shared__ float    hsT[TILE][HSTR];         //  6784 B (transposed h-sums)
    __shared__ unsigned char cjTab[21][GR];      //  1092 B (edge col refl maps, per dv)
    // total 40740 B -> 4 blocks/CU

    const int tid = threadIdx.x;
    const int tj = ((int)blockIdx.x & 7) * TILE;
    const int ti = ((int)blockIdx.x >> 3) * TILE;

    const int Ybi = min(max(ti - 20, 0), IMG - YD);
    const int Ybj = min(max(tj - 20, 0), IMG - YD);
    const bool interior = (ti >= 20) && (ti + 51 <= 255) && (tj >= 20) && (tj + 51 <= 255);

    // ---- stage Y (clipped luminance, fp16) ----
    for (int idx = tid; idx < YD * YD; idx += 256) {
        int a = idx / YD, b = idx - a * YD;
        int g = (Ybi + a) * IMG + (Ybj + b);
        float r  = fminf(fmaxf(rgb[g], 0.f), 1.f);
        float gg = fminf(fmaxf(rgb[NPIX + g], 0.f), 1.f);
        float bb = fminf(fmaxf(rgb[2 * NPIX + g], 0.f), 1.f);
        Yreg[a][b] = (_Float16)(0.299f * r + 0.587f * gg + 0.114f * bb);
    }
    // ---- stage RGBX taps at window-grid coords (UNclipped rgb) ----
    for (int idx = tid; idx < GR * GR; idx += 256) {
        int t = idx / GR, b = idx - t * GR;
        int g = refl(ti - 10 + t) * IMG + refl(tj - 10 + b);
        half4 c;
        c.x = (_Float16)rgb[g];
        c.y = (_Float16)rgb[NPIX + g];
        c.z = (_Float16)rgb[2 * NPIX + g];
        c.w = (_Float16)0.f;
        *(half4*)&Creg4[t][b][0] = c;
    }
    // ---- edge tiles: precompute column refl maps for all 21 dv ----
    if (!interior) {
        for (int idx = tid; idx < 21 * GR; idx += 256) {
            int d = idx / GR, c = idx - d * GR;
            cjTab[d][c] = (unsigned char)(refl(refl(tj - 10 + c) + (d - 10)) - Ybj);
        }
    }
    __syncthreads();

    // ---- persistent y0 (window-grid luminance for this thread's h-task) ----
    const int chunk = tid / GR;              // 0..3 for tid<208
    const int t     = tid - chunk * GR;      // 0..51
    const int c0    = chunk * 8;
    float y0r[28];
    if (tid < 4 * GR) {
        int ri = refl(ti - 10 + t) - Ybi;
        #pragma unroll
        for (int j = 0; j < 28; ++j) {
            int cj = refl(tj - 10 + c0 + j) - Ybj;
            y0r[j] = (float)Yreg[ri][cj];
        }
    }

    const float hv = fmaxf(hptr[0], 0.f);
    const float invh = 1.0f / (hv + 1e-8f);

    const int pb = tid & 31;                 // pixel col (v-phase)
    const int s4 = (tid >> 5) << 2;          // strip start row (0,4,...,28)
    float aR[4], aG[4], aB[4], aW[4];
    #pragma unroll
    for (int k = 0; k < 4; ++k) { aR[k] = 0.f; aG[k] = 0.f; aB[k] = 0.f; aW[k] = 0.f; }

    int du = ((int)blockIdx.y / 21) - 10;
    int dv = ((int)blockIdx.y % 21) - 10;

    for (int o = (int)blockIdx.y; o < NOFF; o += NG) {
        __syncthreads();   // hsT consumed by previous iteration's v-phase

        // ---- fused f + horizontal slide: 52 rows x 4 chunks of 8 outputs ----
        if (tid < 4 * GR) {
            int r2;
            if (interior) r2 = t + 10 + du;
            else          r2 = refl(refl(ti - 10 + t) + du) - Ybi;
            const _Float16* y1row = &Yreg[r2][0];

            float f[28];
            if (interior) {
                const int cb = c0 + 10 + dv;
                if (((10 + dv) & 1) == 0) {          // cb even (c0 mult of 8)
                    const half2_t* q = (const half2_t*)&y1row[cb];
                    #pragma unroll
                    for (int k2 = 0; k2 < 14; ++k2) {
                        half2_t p = q[k2];
                        float d0 = y0r[2 * k2]     - (float)p.x;
                        float d1 = y0r[2 * k2 + 1] - (float)p.y;
                        f[2 * k2]     = d0 * d0;
                        f[2 * k2 + 1] = d1 * d1;
                    }
                } else {                              // cb odd
                    const half2_t* q = (const half2_t*)&y1row[cb - 1];
                    #pragma unroll
                    for (int j = 0; j < 28; ++j) {
                        half2_t p = q[(j + 1) >> 1];  // CSE'd: 15 loads total
                        float yv = (j & 1) ? (float)p.x : (float)p.y;
                        float d = y0r[j] - yv;
                        f[j] = d * d;
                    }
                }
            } else {
                const unsigned char* cj = &cjTab[dv + 10][0];
                #pragma unroll
                for (int j = 0; j < 28; ++j) {
                    float d = y0r[j] - (float)y1row[cj[c0 + j]];
                    f[j] = d * d;
                }
            }
            float s = 0.f;
            #pragma unroll
            for (int j = 0; j < 21; ++j) s += f[j];
            hsT[c0][t] = s;
            #pragma unroll
            for (int k = 1; k < 8; ++k) {
                s += f[20 + k] - f[k - 1];
                hsT[c0 + k][t] = s;
            }
        }
        __syncthreads();

        // ---- vertical slide + weight + accumulate (1x4 strip, all 256 thr) ----
        {
            float vs = 0.f;
            #pragma unroll
            for (int u = 0; u < 21; ++u) vs += hsT[pb][s4 + u];
            const int cr = 10 + du;
            const int cc = pb + 10 + dv;
            #pragma unroll
            for (int k = 0; k < 4; ++k) {
                float dist = sqrtf(fmaxf(vs, 0.f));
                float w = __expf(-dist * invh);
                half4 c = *(const half4*)&Creg4[s4 + k + cr][cc][0];
                aW[k] += w;
                aR[k] += w * (float)c.x;
                aG[k] += w * (float)c.y;
                aB[k] += w * (float)c.z;
                if (k < 3) vs += hsT[pb][s4 + k + 21] - hsT[pb][s4 + k];
            }
        }

        // advance offset by NG=24 (= 21 + 3)
        du += 1; dv += 3;
        if (dv > 10) { dv -= 21; du += 1; }
    }

    // ---- epilogue: one float4 per pixel ----
    #pragma unroll
    for (int k = 0; k < 4; ++k) {
        int gpix = (ti + s4 + k) * IMG + (tj + pb);
        float4 st = make_float4(aR[k], aG[k], aB[k], aW[k]);
        if (DIRECT) {
            partials[(size_t)blockIdx.y * NPIX + gpix] = st;
        } else {
            atomicAdd(&partials[gpix].x, st.x);
            atomicAdd(&partials[gpix].y, st.y);
            atomicAdd(&partials[gpix].z, st.z);
            atomicAdd(&partials[gpix].w, st.w);
        }
    }
}

template <int NGT>
__global__ __launch_bounds__(256)
void nlm_finalize(const float4* __restrict__ partials, float* __restrict__ out)
{
    int idx = blockIdx.x * blockDim.x + threadIdx.x;
    float r = 0.f, g = 0.f, b = 0.f, w = 0.f;
    #pragma unroll
    for (int gg = 0; gg < NGT; ++gg) {
        float4 p = partials[(size_t)gg * NPIX + idx];
        r += p.x; g += p.y; b += p.z; w += p.w;
    }
    float inv = 1.0f / w;   // sum(w) >= 1 (self offset contributes exp(0))
    out[idx]            = fminf(fmaxf(r * inv, 0.f), 1.f);
    out[NPIX + idx]     = fminf(fmaxf(g * inv, 0.f), 1.f);
    out[2 * NPIX + idx] = fminf(fmaxf(b * inv, 0.f), 1.f);
}

extern "C" void kernel_launch(void* const* d_in, const int* in_sizes, int n_in,
                              void* d_out, int out_size, void* d_ws, size_t ws_size,
                              hipStream_t stream) {
    (void)in_sizes; (void)n_in; (void)out_size;
    const float* rgb  = (const float*)d_in[0];
    const float* hptr = (const float*)d_in[1];
    float* out = (float*)d_out;
    float4* partials = (float4*)d_ws;

    const bool direct = ws_size >= (size_t)NG * NPIX * sizeof(float4);  // 25.2 MB
    dim3 grid(64, NG);
    if (direct) {
        nlm_main<true><<<grid, 256, 0, stream>>>(rgb, hptr, partials);
        nlm_finalize<NG><<<NPIX / 256, 256, 0, stream>>>(partials, out);
    } else {
        (void)hipMemsetAsync(partials, 0, (size_t)NPIX * sizeof(float4), stream);
        nlm_main<false><<<grid, 256, 0, stream>>>(rgb, hptr, partials);
        nlm_finalize<1><<<NPIX / 256, 256, 0, stream>>>(partials, out);
    }
}

// Round 6
// 135.106 us; speedup vs baseline: 2.2500x; 1.0041x over previous
//
#include <hip/hip_runtime.h>
#include <math.h>

// NLM S=21, 256x256x3, reflect padding. Round 6:
// - dual-offset rounds: 2 offsets per barrier pair (1 barrier/offset)
// - fp16 hs buffers (2x, 32x54 halves, odd dword stride) -> LDS 40868B, 4 blk/CU
// - chunk-16 h-slides (104 tasks/offset, 36 f-evals) -> -36% f redundancy
// - packed fp16 f-compute (half2 pk_sub/pk_mul)
// - v_dot2_f32_f16 vertical 21-sum (fallback if builtin missing)
// - NG=16: 1024 blocks = exactly one 4-blk/CU residency wave

#define IMG 256
#define NPIX (IMG * IMG)
#define TILE 32
#define GR 52      // TILE + 20 (window-grid dim)
#define YD 72      // TILE + 40 (Y region dim)
#define YSTR 78    // Yreg row stride in halves (39 dwords, odd -> full bank spread)
#define RSTR 54    // hs row stride in halves (27 dwords, odd -> full bank spread)
#define NOFF 441
#define NG 16

typedef __attribute__((ext_vector_type(4))) _Float16 half4;
typedef __attribute__((ext_vector_type(2))) _Float16 half2_t;

#if __has_builtin(__builtin_amdgcn_fdot2)
#define FDOT2(a, b, c) __builtin_amdgcn_fdot2((a), (b), (c), false)
#else
#define FDOT2(a, b, c) ((c) + (float)(a).x * (float)(b).x + (float)(a).y * (float)(b).y)
#endif

__device__ __forceinline__ int refl(int t) {
    t = t < 0 ? -t : t;             // valid for t in [-255, 510]
    return t > 255 ? 510 - t : t;
}

template <bool DIRECT>
__global__ __launch_bounds__(256, 4)
void nlm_main(const float* __restrict__ rgb, const float* __restrict__ hptr,
              float4* __restrict__ partials)
{
    __shared__ _Float16 Yreg[YD][YSTR];          // 11232 B (clipped luminance, fp16)
    __shared__ _Float16 Creg4[GR][GR][4];        // 21632 B (RGBX taps at window grid)
    __shared__ _Float16 hsAB[2][TILE][RSTR];     //  6912 B (h-sums, fp16, dual buffer)
    __shared__ unsigned char cjTab[21][GR];      //  1092 B (col refl maps per dv; [10]=identity)
    // total 40868 B -> 4 blocks/CU

    const int tid = threadIdx.x;
    const int tj = ((int)blockIdx.x & 7) * TILE;
    const int ti = ((int)blockIdx.x >> 3) * TILE;

    const int Ybi = min(max(ti - 20, 0), IMG - YD);
    const int Ybj = min(max(tj - 20, 0), IMG - YD);
    const bool interior = (ti >= 20) && (ti + 51 <= 255) && (tj >= 20) && (tj + 51 <= 255);

    // ---- stage Y (clipped luminance, fp16) ----
    for (int idx = tid; idx < YD * YD; idx += 256) {
        int a = idx / YD, b = idx - a * YD;
        int g = (Ybi + a) * IMG + (Ybj + b);
        float r  = fminf(fmaxf(rgb[g], 0.f), 1.f);
        float gg = fminf(fmaxf(rgb[NPIX + g], 0.f), 1.f);
        float bb = fminf(fmaxf(rgb[2 * NPIX + g], 0.f), 1.f);
        Yreg[a][b] = (_Float16)(0.299f * r + 0.587f * gg + 0.114f * bb);
    }
    // ---- stage RGBX taps at window-grid coords (UNclipped rgb) ----
    for (int idx = tid; idx < GR * GR; idx += 256) {
        int t = idx / GR, b = idx - t * GR;
        int g = refl(ti - 10 + t) * IMG + refl(tj - 10 + b);
        half4 c;
        c.x = (_Float16)rgb[g];
        c.y = (_Float16)rgb[NPIX + g];
        c.z = (_Float16)rgb[2 * NPIX + g];
        c.w = (_Float16)0.f;
        *(half4*)&Creg4[t][b][0] = c;
    }
    // ---- col refl maps for all dv (edge tiles; [10] also = identity y0 map) ----
    if (!interior) {
        for (int idx = tid; idx < 21 * GR; idx += 256) {
            int d = idx / GR, c = idx - d * GR;
            cjTab[d][c] = (unsigned char)(refl(refl(tj - 10 + c) + (d - 10)) - Ybj);
        }
    }

    const float hv = fmaxf(hptr[0], 0.f);
    const float negI = -1.0f / (hv + 1e-8f);

    // h-task decomposition: group g in {0,1} (one offset each), 104 tasks/group
    const int hg    = tid / 104;             // 0,1 (tid<208)
    const int task  = tid - hg * 104;
    const int chunk = task / 52;             // 0,1
    const int t     = task - chunk * 52;     // 0..51
    const int c0    = chunk * 16;

    // v-task decomposition
    const int pb = tid & 31;                 // pixel col
    const int s4 = (tid >> 5) << 2;          // strip start row (0,4,...,28)
    float aR[4], aG[4], aB[4], aW[4];
    #pragma unroll
    for (int k = 0; k < 4; ++k) { aR[k] = 0.f; aG[k] = 0.f; aB[k] = 0.f; aW[k] = 0.f; }

    half2_t one; one.x = (_Float16)1.f; one.y = (_Float16)1.f;

    int duA = -10, dvA = (int)blockIdx.y - 10;

    for (int oA = (int)blockIdx.y; oA < NOFF; oA += 2 * NG) {
        int duB = duA, dvB = dvA + NG;
        if (dvB > 10) { dvB -= 21; duB += 1; }
        const bool hasB = (oA + NG) < NOFF;

        __syncthreads();   // hs buffers free (prev round's v done)

        // ---- h-phase: fused f + 16-wide horizontal slide ----
        if (tid < 208 && (hasB || hg == 0)) {
            const int du = hg ? duB : duA;
            const int dv = hg ? dvB : dvA;
            _Float16* hsb = &hsAB[hg][0][0];

            float f[36];
            if (interior) {
                const _Float16* y0p = &Yreg[t + 10][c0 + 10];
                const _Float16* y1p = &Yreg[t + 10 + du][c0 + 10 + dv];
                if ((dv & 1) == 0) {
                    const half2_t* q0 = (const half2_t*)y0p;
                    const half2_t* q1 = (const half2_t*)y1p;
                    #pragma unroll
                    for (int i = 0; i < 18; ++i) {
                        half2_t d2 = q0[i] - q1[i];
                        half2_t p2 = d2 * d2;
                        f[2 * i]     = (float)p2.x;
                        f[2 * i + 1] = (float)p2.y;
                    }
                } else {
                    const half2_t* q0 = (const half2_t*)y0p;
                    const half2_t* q1 = (const half2_t*)(y1p - 1);
                    half2_t prev = q1[0];
                    #pragma unroll
                    for (int i = 0; i < 18; ++i) {
                        half2_t cur = q1[i + 1];
                        half2_t b; b.x = prev.y; b.y = cur.x;
                        half2_t d2 = q0[i] - b;
                        half2_t p2 = d2 * d2;
                        f[2 * i]     = (float)p2.x;
                        f[2 * i + 1] = (float)p2.y;
                        prev = cur;
                    }
                }
            } else {
                const unsigned char* cj0 = &cjTab[10][0];
                const unsigned char* cj1 = &cjTab[dv + 10][0];
                const _Float16* Y0row = &Yreg[refl(ti - 10 + t) - Ybi][0];
                const _Float16* Y1row = &Yreg[refl(refl(ti - 10 + t) + du) - Ybi][0];
                #pragma unroll
                for (int j = 0; j < 36; ++j) {
                    int c = c0 + j;
                    float d = (float)Y0row[cj0[c]] - (float)Y1row[cj1[c]];
                    f[j] = d * d;
                }
            }
            float s = f[0];
            #pragma unroll
            for (int j = 1; j < 21; ++j) s += f[j];
            hsb[c0 * RSTR + t] = (_Float16)s;
            #pragma unroll
            for (int k = 1; k < 16; ++k) {
                s += f[20 + k] - f[k - 1];
                hsb[(c0 + k) * RSTR + t] = (_Float16)s;
            }
        }
        __syncthreads();

        // ---- v-phase: both offsets, all 256 threads ----
        #pragma unroll
        for (int g = 0; g < 2; ++g) {
            if (g == 1 && !hasB) break;
            const int du = g ? duB : duA;
            const int dv = g ? dvB : dvA;
            const half2_t* col = (const half2_t*)&hsAB[g][pb][s4];  // s4,RSTR even -> aligned

            half2_t v[12];
            #pragma unroll
            for (int i = 0; i < 12; ++i) v[i] = col[i];
            float vs = 0.f;
            #pragma unroll
            for (int i = 0; i < 10; ++i) vs = FDOT2(v[i], one, vs);
            vs += (float)v[10].x;

            float vss[4];
            vss[0] = vs;
            vss[1] = vss[0] + (float)v[10].y - (float)v[0].x;
            vss[2] = vss[1] + (float)v[11].x - (float)v[0].y;
            vss[3] = vss[2] + (float)v[11].y - (float)v[1].x;

            const int cr = 10 + du;
            const int cc = pb + 10 + dv;
            #pragma unroll
            for (int k = 0; k < 4; ++k) {
                float dist = sqrtf(fmaxf(vss[k], 0.f));
                float w = __expf(dist * negI);
                half4 c = *(const half4*)&Creg4[s4 + k + cr][cc][0];
                aW[k] += w;
                aR[k] += w * (float)c.x;
                aG[k] += w * (float)c.y;
                aB[k] += w * (float)c.z;
            }
        }

        // advance A by 32 offsets (two wraps of 16)
        duA = duB; dvA = dvB + NG;
        if (dvA > 10) { dvA -= 21; duA += 1; }
    }

    // ---- epilogue: one float4 per pixel ----
    #pragma unroll
    for (int k = 0; k < 4; ++k) {
        int gpix = (ti + s4 + k) * IMG + (tj + pb);
        float4 st = make_float4(aR[k], aG[k], aB[k], aW[k]);
        if (DIRECT) {
            partials[(size_t)blockIdx.y * NPIX + gpix] = st;
        } else {
            float* p = (float*)&partials[gpix];
            atomicAdd(p + 0, st.x);
            atomicAdd(p + 1, st.y);
            atomicAdd(p + 2, st.z);
            atomicAdd(p + 3, st.w);
        }
    }
}

template <int NGT>
__global__ __launch_bounds__(256)
void nlm_finalize(const float4* __restrict__ partials, float* __restrict__ out)
{
    int idx = blockIdx.x * blockDim.x + threadIdx.x;
    float r = 0.f, g = 0.f, b = 0.f, w = 0.f;
    #pragma unroll
    for (int gg = 0; gg < NGT; ++gg) {
        float4 p = partials[(size_t)gg * NPIX + idx];
        r += p.x; g += p.y; b += p.z; w += p.w;
    }
    float inv = 1.0f / w;   // sum(w) >= 1 (self offset contributes exp(0))
    out[idx]            = fminf(fmaxf(r * inv, 0.f), 1.f);
    out[NPIX + idx]     = fminf(fmaxf(g * inv, 0.f), 1.f);
    out[2 * NPIX + idx] = fminf(fmaxf(b * inv, 0.f), 1.f);
}

extern "C" void kernel_launch(void* const* d_in, const int* in_sizes, int n_in,
                              void* d_out, int out_size, void* d_ws, size_t ws_size,
                              hipStream_t stream) {
    (void)in_sizes; (void)n_in; (void)out_size;
    const float* rgb  = (const float*)d_in[0];
    const float* hptr = (const float*)d_in[1];
    float* out = (float*)d_out;
    float4* partials = (float4*)d_ws;

    const bool direct = ws_size >= (size_t)NG * NPIX * sizeof(float4);  // 16.8 MB
    dim3 grid(64, NG);
    if (direct) {
        nlm_main<true><<<grid, 256, 0, stream>>>(rgb, hptr, partials);
        nlm_finalize<NG><<<NPIX / 256, 256, 0, stream>>>(partials, out);
    } else {
        (void)hipMemsetAsync(partials, 0, (size_t)NPIX * sizeof(float4), stream);
        nlm_main<false><<<grid, 256, 0, stream>>>(rgb, hptr, partials);
        nlm_finalize<1><<<NPIX / 256, 256, 0, stream>>>(partials, out);
    }
}